// Round 13
// baseline (2381.666 us; speedup 1.0000x reference)
//
#include <hip/hip_runtime.h>

#define HH 32
#define LOG2E 1.44269504088896340736f
#define KCH 16   // TF pipeline chunk length (steps per ring half)

typedef float v2f __attribute__((ext_vector_type(2)));

// DPP (all VALU-pipe): quad_perm broadcasts, row rotates, row broadcasts
#define DPPF(v, ctrl) \
    __int_as_float(__builtin_amdgcn_update_dpp(0, __float_as_int(v), (ctrl), 0xF, 0xF, true))
#define QP_B0 0x00   // quad bcast lane0 -> gate i
#define QP_B1 0x55   // gate f
#define QP_B2 0xAA   // gate g
#define QP_B3 0xFF   // gate o
#define ROR4  0x124  // row_ror:4  (same-q, stride-4 within 16-lane row)
#define ROR8  0x128  // row_ror:8
#define BC15  0x142  // row_bcast:15
#define BC31  0x143  // row_bcast:31

__device__ __forceinline__ float hw_exp2(float x) {
    float r; asm("v_exp_f32 %0, %1" : "=v"(r) : "v"(x)); return r;
}
__device__ __forceinline__ float sigm_e(float z, float e) {
    return __builtin_amdgcn_rcpf(1.0f + hw_exp2(z * e));
}
__device__ __forceinline__ v2f pk_fma(v2f a, v2f b, v2f c) {
    return __builtin_elementwise_fma(a, b, c);   // v_pk_fma_f32, ACC folds
}
__device__ __forceinline__ void load_bc(const float* p, v2f* d) {
#pragma unroll
    for (int r = 0; r < 8; ++r) {                // 8x ds_read_b128 broadcast
        float4 v = ((const float4*)p)[r];
        d[2*r]   = (v2f){v.x, v.y};
        d[2*r+1] = (v2f){v.z, v.w};
    }
}
// Sum pr over 32 channels (pr is q-redundant per (q,ch)); returns uniform scalar.
// ror4+ror8 sum the 4 same-q lanes per row; bcast15/31 combine the 4 rows; lane63=total.
__device__ __forceinline__ float chan_reduce(float p) {
    p += DPPF(p, ROR4);
    p += DPPF(p, ROR8);
    p += DPPF(p, BC15);
    p += DPPF(p, BC31);
    return __int_as_float(__builtin_amdgcn_readlane(__float_as_int(p), 63));
}
// gate nonlinearity + cell update; h valid (redundantly) on ALL lanes
__device__ __forceinline__ void gates(float zA, float zB, float es, float mm, float cc,
                                      float& cSA, float& cSB, float& hA, float& hB) {
    float acA = fmaf(mm, sigm_e(zA, es), cc);
    float acB = fmaf(mm, sigm_e(zB, es), cc);
    float iA = DPPF(acA, QP_B0), fA = DPPF(acA, QP_B1);
    float gA = DPPF(acA, QP_B2), oA = DPPF(acA, QP_B3);
    float iB = DPPF(acB, QP_B0), fB = DPPF(acB, QP_B1);
    float gB = DPPF(acB, QP_B2), oB = DPPF(acB, QP_B3);
    cSA = fmaf(fA, cSA, iA * gA);
    cSB = fmaf(fB, cSB, iB * gB);
    hA = oA * fmaf(2.0f, sigm_e(cSA, -2.0f * LOG2E), -1.0f);
    hB = oB * fmaf(2.0f, sigm_e(cSB, -2.0f * LOG2E), -1.0f);
}
__device__ __forceinline__ void dot16(const v2f* h, const v2f* mA, const v2f* mB,
                                      v2f& r0, v2f& r1, v2f& r2, v2f& r3) {
#pragma unroll
    for (int r = 0; r < 16; r += 2) {
        r0 = pk_fma(h[r],   mA[r],   r0);
        r1 = pk_fma(h[r+1], mA[r+1], r1);
        r2 = pk_fma(h[r],   mB[r],   r2);
        r3 = pk_fma(h[r+1], mB[r+1], r3);
    }
}

// Layout: q=lane&3 (gate 0=i 1=f 2=g 3=o), ch=lane>>2 (0..15).
// Lane owns rows rowA=(q<<5)|ch and rowB=(q<<5)|(ch+16) of each 128-row matrix.
__global__ __launch_bounds__(128, 2)
void lstm_seq_kernel(const float* __restrict__ input,
                     const float* __restrict__ W_ih1, const float* __restrict__ W_hh1,
                     const float* __restrict__ b_ih1, const float* __restrict__ b_hh1,
                     const float* __restrict__ W_ih2, const float* __restrict__ W_hh2,
                     const float* __restrict__ b_ih2, const float* __restrict__ b_hh2,
                     const float* __restrict__ W_lin, const float* __restrict__ b_lin,
                     float* __restrict__ out, int T, int total)
{
    const int b    = blockIdx.x;
    const int tid  = threadIdx.x;
    const int w    = tid >> 6;       // wave0 = cell1 producer (TF only); wave1 = rest
    const int lane = tid & 63;
    const int q    = lane & 3;
    const int ch   = lane >> 2;
    const int rowA = (q << 5) | ch;
    const int rowB = (q << 5) | (ch + 16);

    __shared__ __align__(16) float ring[2 * KCH * HH];
    __shared__ __align__(16) float h1s[HH];
    __shared__ __align__(16) float h2s[HH];
    __shared__ __align__(16) float zbuf[128];   // TF->AR: z1 partial handoff
    __shared__ __align__(16) float cbuf[HH];    // TF->AR: c1 state handoff

    const bool  isg = (q == 2);
    const float es  = isg ? (-2.0f * LOG2E) : (-LOG2E);
    const float mm  = isg ? 2.0f : 1.0f;
    const float cc  = isg ? -1.0f : 0.0f;

    const float* __restrict__ inp  = input + (size_t)b * T;
    float* __restrict__       outp = out   + (size_t)b * total;

    if (w == 0) {
        // ================= wave0: TF cell-1 producer, then exit =================
        v2f m1A[16], m1B[16];            // W_hh1
        {
            const v2f* pA = (const v2f*)(W_hh1 + rowA * HH);
            const v2f* pB = (const v2f*)(W_hh1 + rowB * HH);
#pragma unroll
            for (int r = 0; r < 16; ++r) { m1A[r] = pA[r]; m1B[r] = pB[r]; }
        }
        const float wxA = W_ih1[rowA], wxB = W_ih1[rowB];
        const float bA  = b_ih1[rowA] + b_hh1[rowA];
        const float bB  = b_ih1[rowB] + b_hh1[rowB];
        float cA = 0.f, cB = 0.f;
        v2f p0 = {0,0}, p1 = {0,0}, p2 = {0,0}, p3 = {0,0};
        float xcur = inp[0];
        int t = 0;
        for (int cb = 0; t < T; ++cb) {
            float* buf = ring + (cb & 1) * (KCH * HH);
            int S = T - t; if (S > KCH) S = KCH;
            for (int s = 0; s < S; ++s, ++t) {
                float x = xcur;
                int tn = t + 1;
                xcur = inp[tn < T ? tn : 0];
                float z1A = fmaf(x, wxA, bA + (p0.x + p0.y) + (p1.x + p1.y));
                float z1B = fmaf(x, wxB, bB + (p2.x + p2.y) + (p3.x + p3.y));
                float hA, hB;
                gates(z1A, z1B, es, mm, cc, cA, cB, hA, hB);
                float* slot = buf + s * HH;
                if (q == 0) { slot[ch] = hA; slot[ch + 16] = hB; }
                v2f hv[16]; load_bc(slot, hv);
                p0 = (v2f){0,0}; p1 = (v2f){0,0}; p2 = (v2f){0,0}; p3 = (v2f){0,0};
                dot16(hv, m1A, m1B, p0, p1, p2, p3);
            }
            __syncthreads();                       // chunk published
        }
        // handoff: z1 partial for t=T (incl bias) + c1 state
        zbuf[lane]      = bA + (p0.x + p0.y) + (p1.x + p1.y);
        zbuf[64 + lane] = bB + (p2.x + p2.y) + (p3.x + p3.y);
        if (q == 0) { cbuf[ch] = cA; cbuf[16 + ch] = cB; }
        __syncthreads();                           // final barrier (matches consumer)
        return;                                    // wave0 done
    }

    // ================= wave1: TF cell-2 consumer, then single-wave AR ============
    v2f m1A[16], m1B[16], m2A[16], m2B[16];        // W_ih2, W_hh2
    {
        const v2f* pA = (const v2f*)(W_ih2 + rowA * HH);
        const v2f* pB = (const v2f*)(W_ih2 + rowB * HH);
        const v2f* qA = (const v2f*)(W_hh2 + rowA * HH);
        const v2f* qB = (const v2f*)(W_hh2 + rowB * HH);
#pragma unroll
        for (int r = 0; r < 16; ++r) { m1A[r] = pA[r]; m1B[r] = pB[r];
                                       m2A[r] = qA[r]; m2B[r] = qB[r]; }
    }
    const float bA  = b_ih2[rowA] + b_hh2[rowA];
    const float bB  = b_ih2[rowB] + b_hh2[rowB];
    const float wlA = W_lin[ch], wlB = W_lin[ch + 16], blin = b_lin[0];

    float cA = 0.f, cB = 0.f;                      // c2
    v2f p0 = {0,0}, p1 = {0,0}, p2 = {0,0}, p3 = {0,0};  // e-carry = Whh2·h2(t-1)
    float ov_s = 0.0f;

    __syncthreads();                               // wait chunk 0
    int t = 0;
    for (int cb = 0; t < T; ++cb) {
        const float* buf = ring + (cb & 1) * (KCH * HH);
        int S = T - t; if (S > KCH) S = KCH;
        v2f hv[16]; load_bc(buf, hv);              // slot 0
        for (int s = 0; s < S; ++s, ++t) {
            v2f s0 = p0, s1 = p1, s2 = p2, s3 = p3;
            dot16(hv, m1A, m1B, s0, s1, s2, s3);   // consumes hv
            if (s + 1 < S) load_bc(buf + (s + 1) * HH, hv);   // prefetch next slot
            float z2A = bA + (s0.x + s0.y) + (s1.x + s1.y);
            float z2B = bB + (s2.x + s2.y) + (s3.x + s3.y);
            float hA, hB;
            gates(z2A, z2B, es, mm, cc, cA, cB, hA, hB);
            if (q == 0) { h2s[ch] = hA; h2s[ch + 16] = hB; }
            v2f gv[16]; load_bc(h2s, gv);
            float pr = fmaf(hA, wlA, hB * wlB);    // VALU reduce fills gv latency
            ov_s = chan_reduce(pr) + blin;
            if (lane == 0) outp[t] = ov_s;
            p0 = (v2f){0,0}; p1 = (v2f){0,0}; p2 = (v2f){0,0}; p3 = (v2f){0,0};
            dot16(gv, m2A, m2B, p0, p1, p2, p3);   // e-carry for next step
        }
        __syncthreads();
    }

    // ---- AR init: load cell-1 weights now (kept out of TF live range) ----
    v2f m3A[16], m3B[16];                          // W_hh1
    {
        const v2f* pA = (const v2f*)(W_hh1 + rowA * HH);
        const v2f* pB = (const v2f*)(W_hh1 + rowB * HH);
#pragma unroll
        for (int r = 0; r < 16; ++r) { m3A[r] = pA[r]; m3B[r] = pB[r]; }
    }
    const float wxA = W_ih1[rowA], wxB = W_ih1[rowB];
    const float b1A = b_ih1[rowA] + b_hh1[rowA];
    const float b1B = b_ih1[rowB] + b_hh1[rowB];
    float aA  = zbuf[lane], aB = zbuf[64 + lane];  // b1 + Whh1·h1(T-1)
    float c1A = cbuf[ch],  c1B = cbuf[16 + ch];

    // ================= AR: single wave, zero barriers =================
    for (int t2 = T; t2 < total; ++t2) {
        float x = ov_s;                            // feedback in-register (uniform)
        float z1A = fmaf(x, wxA, aA);
        float z1B = fmaf(x, wxB, aB);
        float h1A, h1B;
        gates(z1A, z1B, es, mm, cc, c1A, c1B, h1A, h1B);
        if (q == 0) { h1s[ch] = h1A; h1s[ch + 16] = h1B; }
        v2f hv[16]; load_bc(h1s, hv);              // same-wave round trip
        v2f s0 = p0, s1 = p1, s2 = p2, s3 = p3;
        dot16(hv, m1A, m1B, s0, s1, s2, s3);       // z2 = e + Wih2·h1
        // a-carry for next step (independent of cell-2 chain; scheduler overlaps)
        v2f q0 = {0,0}, q1 = {0,0}, q2 = {0,0}, q3 = {0,0};
        dot16(hv, m3A, m3B, q0, q1, q2, q3);
        aA = b1A + (q0.x + q0.y) + (q1.x + q1.y);
        aB = b1B + (q2.x + q2.y) + (q3.x + q3.y);
        float z2A = bA + (s0.x + s0.y) + (s1.x + s1.y);
        float z2B = bB + (s2.x + s2.y) + (s3.x + s3.y);
        float h2A, h2B;
        gates(z2A, z2B, es, mm, cc, cA, cB, h2A, h2B);
        if (q == 0) { h2s[ch] = h2A; h2s[ch + 16] = h2B; }
        v2f gv[16]; load_bc(h2s, gv);
        float pr = fmaf(h2A, wlA, h2B * wlB);      // out dot, all-VALU reduce
        ov_s = chan_reduce(pr) + blin;
        if (lane == 0) outp[t2] = ov_s;
        p0 = (v2f){0,0}; p1 = (v2f){0,0}; p2 = (v2f){0,0}; p3 = (v2f){0,0};
        dot16(gv, m2A, m2B, p0, p1, p2, p3);       // e-carry for next step
    }
}

extern "C" void kernel_launch(void* const* d_in, const int* in_sizes, int n_in,
                              void* d_out, int out_size, void* d_ws, size_t ws_size,
                              hipStream_t stream) {
    const int B = 1024;                 // fixed by the source module
    const int T = in_sizes[0] / B;      // 999
    const int total = out_size / B;     // T + future = 1999

    lstm_seq_kernel<<<dim3(B), dim3(128), 0, stream>>>(
        (const float*)d_in[0],
        (const float*)d_in[1], (const float*)d_in[2],
        (const float*)d_in[3], (const float*)d_in[4],
        (const float*)d_in[5], (const float*)d_in[6],
        (const float*)d_in[7], (const float*)d_in[8],
        (const float*)d_in[9], (const float*)d_in[10],
        (float*)d_out, T, total);
}